// Round 12
// baseline (1489.682 us; speedup 1.0000x reference)
//
#include <hip/hip_runtime.h>
#include <hip/hip_bf16.h>
#include <stdint.h>

typedef __bf16 bf16_t;
typedef __bf16 bf16x8 __attribute__((ext_vector_type(8)));
typedef float  f32x4  __attribute__((ext_vector_type(4)));

#define HP 514   // padded spatial width (512 + 2)
#define AS1 __attribute__((address_space(1)))
#define AS3 __attribute__((address_space(3)))

__device__ __forceinline__ bf16_t f2bf(float f) { return (bf16_t)f; }

// ---------- L0: 1->64 1x1 conv + PReLU; fp32 NCHW -> padded NHWC bf16 ----------
__global__ void l0_kernel(const float* __restrict__ A, const float* __restrict__ w0,
                          const float* __restrict__ b0, const float* __restrict__ p0,
                          bf16_t* __restrict__ X0)
{
    int idx = blockIdx.x * 256 + threadIdx.x;
    if (idx >= HP * HP * 64) return;
    int c   = idx & 63;
    int pix = idx >> 6;
    int py = pix / HP, px = pix - py * HP;
    float v = 0.f;
    if (py >= 1 && py <= 512 && px >= 1 && px <= 512) {
        float a = A[(py - 1) * 512 + (px - 1)];
        v = fmaf(w0[c], a, b0[c]);
        v = v >= 0.f ? v : p0[0] * v;
    }
    X0[idx] = f2bf(v);
}

// ---------- zero full rows [r0, r0+n) of a strip buffer ----------
__global__ void zero_rows_kernel(bf16_t* __restrict__ buf, int C, int r0, int n)
{
    int idx = blockIdx.x * 256 + threadIdx.x;
    int rowsz = HP * C;
    if (idx >= n * rowsz) return;
    int r = idx / rowsz, j = idx - r * rowsz;
    buf[(size_t)(r0 + r) * rowsz + j] = f2bf(0.f);
}

// ---------- zero cols 0 and 513 for rows [0, R) ----------
__global__ void zero_cols_kernel(bf16_t* __restrict__ buf, int C, int R)
{
    int idx = blockIdx.x * 256 + threadIdx.x;
    if (idx >= R * 2 * C) return;
    int r = idx / (2 * C);
    int t = idx - r * 2 * C;
    int col = (t < C) ? 0 : 513;
    int c = t % C;
    buf[((size_t)r * HP + col) * C + c] = f2bf(0.f);
}

// ---------- weight transform: OIHW fp32 -> MFMA-fragment-ordered bf16 ----------
// wt[(((ci*9 + tap)*G + gabs)*64 + l)*8 + j] = w[(cout*CIN+cin)*9 + tap]
//   cout = gabs*16 + (l&15), cin = ci*32 + (l>>4)*8 + j, G = COUT/16
// (correctness verified in R3/R4 runs)
__global__ void wtrans_kernel(const float* __restrict__ w, bf16_t* __restrict__ wt,
                              int COUT, int CIN)
{
    int idx = blockIdx.x * 256 + threadIdx.x;
    if (idx >= COUT * CIN * 9) return;
    int G    = COUT / 16;
    int j    = idx & 7;
    int l    = (idx >> 3) & 63;
    int t    = idx >> 9;
    int gabs = t % G;
    int t2   = t / G;
    int tap  = t2 % 9;
    int ci   = t2 / 9;
    int cout = gabs * 16 + (l & 15);
    int cin  = ci * 32 + (l >> 4) * 8 + j;
    wt[idx] = f2bf(w[(cout * CIN + cin) * 9 + tap]);
}

// ---------- 3x3 conv + bias + PReLU, implicit GEMM, bf16 MFMA ----------
// R6:  B direct global->reg (wt fragment-ordered, L2-resident); A via
//      global_load_lds with inverse-swizzled source.
// R7:  A-fragment register prefetch (ping-pong) + s_setprio around MFMA.
// R9/R10: XCD-aware bijective swizzle, z-innermost; coalesced LDS epilogue.
// R12: 4-slab A staging; readA prefetch every phase.
// R14: counted-vmcnt barrier (vmcnt(NT)+s_barrier); NC==2 barrier-free.
// (Dead ends: depth-2 B prefetch thrashes L2 (R8/R11); 32x32 shape kills
//  acc-chain ILP (R13).)
// R15/R16: 8 waves/block (512 thr), 2m x 4n wave split; per-wave tile 64px
//      x BN/4: acc 32 AGPR, ~110 regs < 128 -> 4 waves/SIMD (+33% TLP).
//      R16 FIX of R15's correctness bug: staging pass 1 (units 512..1023)
//      overflowed the 768-unit slab for waves 4-7 (units >= 768 corrupted
//      the NEXT slab). Pass 1 is now issued by waves 0-3 only (they cover
//      real units 512..719 + in-slab pad 720..767); waves 4-7 skip it.
template<int CIN, int COUT, int BN>
__global__ __launch_bounds__(512, 4)
void conv3x3_kernel(const bf16_t* __restrict__ in, const bf16_t* __restrict__ wt,
                    const float* __restrict__ bias, const float* __restrict__ alpha,
                    bf16_t* __restrict__ out,
                    int n_rows, int in_off, int in_alloc, int out_off)
{
    constexpr int G      = COUT / 16;     // global cout groups (wt layout)
    constexpr int NT     = BN / 64;       // 16-groups per wave (2 or 1)
    constexpr int NC     = CIN / 32;      // channel chunks (even: 2,8,16)
    constexpr int AUNITS = 18 * 10 * 4;   // 720 16B-units
    constexpr int APAD   = 768;           // padded (pad units 720..767)
    constexpr int ASLAB  = APAD * 8;      // 6144 elems per A slab
    constexpr int ROWB   = BN * 2;        // epilogue tile row bytes
    constexpr int SMASK  = ROWB / 32 - 1; // XOR swizzle mask (7 or 3)
    constexpr int SMEM_B = (4 * ASLAB * 2 > 128 * ROWB) ? 4 * ASLAB * 2 : 128 * ROWB;
    __shared__ __align__(16) char smem[SMEM_B];
    bf16_t* As = (bf16_t*)smem;

    const int tid  = threadIdx.x;
    const int lane = tid & 63;
    const int wave = tid >> 6;           // 0..7
    const int lm   = lane & 15;
    const int quad = lane >> 4;
    const int wave_m = wave >> 2;        // 0..1 (64-px half)
    const int wave_n = wave & 3;         // 0..3 (cout quarter)

    // counted-vmcnt barrier: allow the NT B-loads issued this phase to stay
    // in flight; drain everything older (incl. stageA) before s_barrier.
    auto barrier_cnt = [&]() {
        if constexpr (NT == 2)
            asm volatile("s_waitcnt vmcnt(2)\n\ts_barrier" ::: "memory");
        else
            asm volatile("s_waitcnt vmcnt(1)\n\ts_barrier" ::: "memory");
    };

    // ---- XCD swizzle: hw-linear bid -> chunked sid -> (z inner, x, y outer)
    const int bid  = blockIdx.x + 64 * (blockIdx.y + gridDim.y * blockIdx.z);
    const int nwg  = 64 * gridDim.y * gridDim.z;
    const int sid  = (bid & 7) * (nwg >> 3) + (bid >> 3);
    const int zsh  = __ffs(gridDim.z) - 1;          // gridDim.z in {1,2,4}
    const int szb  = sid & (gridDim.z - 1);
    const int t2   = sid >> zsh;
    const int sx   = t2 & 63;
    const int syb  = t2 >> 6;

    const int x0 = sx * 8;               // input col base (padded coords)
    const int y0 = syb * 16;             // local out row base
    const int zb = szb;
    const int gb_blk = zb * (BN / 16);

    // ---- A staging source map: pass 0 = units 0..511 (all waves), pass 1 =
    // units 512..767 (waves 0..3 ONLY; >=768 would overflow the slab).
    // INVERSE swizzle on the per-lane global address, LDS written linearly.
    int a_srcb[2];
    #pragma unroll
    for (int it = 0; it < 2; ++it) {
        int u  = it * 512 + tid;
        int uu = u < AUNITS ? u : AUNITS - 1;   // pad lanes re-read unit 719
        int qq = uu & 3, px = (uu >> 2) % 10, r = uu / 40;
        int q  = (qq - (px >> 1)) & 3;
        int grow = in_off + y0 + r;
        grow = grow < 0 ? 0 : (grow >= in_alloc ? in_alloc - 1 : grow);
        a_srcb[it] = (grow * HP + x0 + px) * CIN + q * 8;
    }

    // ---- fragment read bases (swizzled; unchanged from R4-verified) ----
    const int pxb = lm & 7, pyb = lm >> 3;
    int sw[3];
    #pragma unroll
    for (int dx = 0; dx < 3; ++dx)
        sw[dx] = ((quad + ((pxb + dx) >> 1)) & 3) * 8;
    int addrA0[4];
    #pragma unroll
    for (int mt = 0; mt < 4; ++mt)
        addrA0[mt] = ((wave_m * 8 + mt * 2 + pyb) * 40 + pxb * 4) * 8;

    // stage chunk (element offset cc = chunk*32) into slab at LDS elem base
    auto stageA = [&](int cc, int base) {
        {   // pass 0: units 0..511, all waves
            const bf16_t* src = in + a_srcb[0] + cc;
            bf16_t* dst = As + base + (wave * 64) * 8;
            __builtin_amdgcn_global_load_lds((AS1 void*)src, (AS3 void*)dst, 16, 0, 0);
        }
        if (wave < 4) {  // pass 1: units 512..767 only (slab bound)
            const bf16_t* src = in + a_srcb[1] + cc;
            bf16_t* dst = As + base + (512 + wave * 64) * 8;
            __builtin_amdgcn_global_load_lds((AS1 void*)src, (AS3 void*)dst, 16, 0, 0);
        }
    };
    // B fragments: direct global -> regs, coalesced 16B/lane (depth 1!)
    auto loadB = [&](int ft, bf16x8* b) {
        const bf16_t* base = wt + ((size_t)ft * G + gb_blk + wave_n * NT) * 512 + lane * 8;
        #pragma unroll
        for (int nt = 0; nt < NT; ++nt)
            b[nt] = *(const bf16x8*)(base + nt * 512);
    };
    // A fragments for (slab base, tap) -> registers (tap compile-time)
    auto readA = [&](int base, int tap, bf16x8* a) {
        const int dy = tap / 3, dx = tap - dy * 3;
        const int shift = (dy * 40 + dx * 4) * 8 + sw[dx];
        #pragma unroll
        for (int mt = 0; mt < 4; ++mt)
            a[mt] = *(const bf16x8*)(As + base + addrA0[mt] + shift);
    };

    f32x4 acc[4][NT] = {};
    bf16x8 breg[2][NT];
    bf16x8 areg[2][4];

    // prologue: chunks 0,1 -> slabs 0,1; flat-0 B; rf=0 A frags
    // (full __syncthreads: vmcnt(0) drain publishes prologue stages)
    stageA(0, 0);
    stageA(32, ASLAB);
    loadB(0, breg[0]);
    __syncthreads();
    readA(0, 0, areg[0]);

    for (int cp = 0; cp < NC / 2; ++cp) {
        const bool morecp = (cp + 1 < NC / 2);
        const int fb  = cp * 18;
        const int sb0 = ((2 * cp)     & 3) * ASLAB;  // chunk 2cp
        const int sb1 = ((2 * cp + 1) & 3) * ASLAB;  // chunk 2cp+1
        const int sb2 = ((2 * cp + 2) & 3) * ASLAB;  // chunk 2cp+2 (restage)
        const int sb3 = ((2 * cp + 3) & 3) * ASLAB;  // chunk 2cp+3 (restage)
        #pragma unroll
        for (int rf = 0; rf < 18; ++rf) {          // fully unrolled: reg
            // B prefetch depth 1 (R10-verified; depth 2 thrashes L2)
            if (rf < 17 || morecp)
                loadB(fb + rf + 1, breg[(rf + 1) & 1]);
            if (rf == 0 && 2 * cp + 2 < NC) stageA((2 * cp + 2) * 32, sb2);
            if (rf == 9 && 2 * cp + 3 < NC) stageA((2 * cp + 3) * 32, sb3);
            // A-fragment prefetch for phase rf+1 -- EVERY phase (all reads
            // target slabs staged >=1 barrier ago)
            if (rf <= 7)        readA(sb0, rf + 1, areg[(rf + 1) & 1]);
            else if (rf == 8)   readA(sb1, 0, areg[1]);
            else if (rf <= 16)  readA(sb1, rf - 8, areg[(rf + 1) & 1]);
            else if (morecp)    readA(sb2, 0, areg[0]);       // rf==17

            __builtin_amdgcn_s_setprio(1);
            #pragma unroll
            for (int mt = 0; mt < 4; ++mt)
                #pragma unroll
                for (int nt = 0; nt < NT; ++nt)
                    acc[mt][nt] = __builtin_amdgcn_mfma_f32_16x16x32_bf16(
                        areg[rf & 1][mt], breg[rf & 1][nt], acc[mt][nt], 0, 0, 0);
            __builtin_amdgcn_s_setprio(0);

            // counted-vmcnt barriers; skipped entirely for NC==2 (no slab
            // is ever overwritten after the prologue stages)
            if (NC > 2 && rf == 8)             barrier_cnt();
            if (NC > 2 && rf == 17 && morecp)  barrier_cnt();
        }
    }

    // ---- epilogue: bias + PReLU -> LDS tile (XOR-swizzled cols) ->
    //      coalesced bf16x8 copy-out (R10-verified values; R15 mapping:
    //      c = (wave_n*NT + nt)*16 + lm, m = wave_m*64 + mt*16 + quad*4 + r).
    __syncthreads();                               // all As reads done; reuse smem
    const float al = alpha[0];
    #pragma unroll
    for (int nt = 0; nt < NT; ++nt) {
        const int c  = (wave_n * NT + nt) * 16 + lm;
        const float bv = bias[zb * BN + c];
        #pragma unroll
        for (int mt = 0; mt < 4; ++mt) {
            f32x4 v = acc[mt][nt];
            #pragma unroll
            for (int r = 0; r < 4; ++r) {
                int m = wave_m * 64 + mt * 16 + quad * 4 + r;
                float f = v[r] + bv;
                f = f >= 0.f ? f : al * f;
                int byte = m * ROWB + ((c * 2) ^ ((m & SMASK) << 5));
                *(bf16_t*)(smem + byte) = f2bf(f);
            }
        }
    }
    __syncthreads();
    constexpr int CPI  = ROWB / 16;                // 16B chunks per pixel
    constexpr int ITER = (128 * CPI) / 512;        // copy iterations
    #pragma unroll
    for (int i = 0; i < ITER; ++i) {
        int g = i * 512 + tid;
        int p = g / CPI;                           // pixel 0..127
        int k = g & (CPI - 1);                     // 16B chunk in row
        int sbyte = p * ROWB + ((k * 16) ^ ((p & SMASK) << 5));
        bf16x8 v16 = *(const bf16x8*)(smem + sbyte);
        int py = p >> 3, px = p & 7, ly = y0 + py;
        if (ly < n_rows)
            *(bf16x8*)(out + ((size_t)(out_off + ly) * HP + (x0 + px + 1)) * COUT
                       + zb * BN + k * 8) = v16;
    }
}

// ---------- L5 (64->1, k3) + bias + PReLU per strip, fp32 T out ----------
__device__ __forceinline__ float conv64_at(const bf16_t* __restrict__ X,
                                           const float* __restrict__ wsh,
                                           int y, int x, float bv)
{
    float acc = bv;
    #pragma unroll
    for (int dy = 0; dy < 3; ++dy) {
        #pragma unroll
        for (int dx = 0; dx < 3; ++dx) {
            const bf16x8* p = (const bf16x8*)(X + ((size_t)(y + dy) * HP + (x + dx)) * 64);
            const float* wf = wsh + (dy * 3 + dx) * 64;
            #pragma unroll
            for (int j = 0; j < 8; ++j) {
                bf16x8 v = p[j];
                #pragma unroll
                for (int k = 0; k < 8; ++k)
                    acc = fmaf((float)v[k], wf[j * 8 + k], acc);
            }
        }
    }
    return acc;
}

__global__ __launch_bounds__(256)
void l5_strip_kernel(const bf16_t* __restrict__ B4, const bf16_t* __restrict__ wt5,
                     const float* __restrict__ b5, const float* __restrict__ p5,
                     float* __restrict__ T, int abs_row0)
{
    __shared__ float wsh[9 * 64];
    for (int i = threadIdx.x; i < 576; i += 256) wsh[i] = (float)wt5[i];
    __syncthreads();
    int idx = blockIdx.x * 256 + threadIdx.x;
    int ly = idx >> 9, x = idx & 511;
    float bv = b5[0], al = p5[0];
    float t = conv64_at(B4, wsh, ly, x, bv);
    t = t >= 0.f ? t : al * t;
    T[(size_t)(abs_row0 + ly) * 512 + x] = t;
}

// ---------- weight transform for L5 (plain [tap][cin], tiny) ----------
__global__ void wtrans5_kernel(const float* __restrict__ w, bf16_t* __restrict__ wt)
{
    int idx = blockIdx.x * 256 + threadIdx.x;
    if (idx >= 9 * 64) return;
    int cin = idx % 64, tap = idx / 64;
    wt[idx] = f2bf(w[cin * 9 + tap]);
}

// ---------- final symmetrize ----------
__global__ __launch_bounds__(256)
void sym_kernel(const float* __restrict__ T, float* __restrict__ out)
{
    int idx = blockIdx.x * 256 + threadIdx.x;
    int y = idx >> 9, x = idx & 511;
    out[idx] = 0.5f * (T[idx] + T[x * 512 + y]);
}

// ----------------------------------------------------------------------------
extern "C" void kernel_launch(void* const* d_in, const int* in_sizes, int n_in,
                              void* d_out, int out_size, void* d_ws, size_t ws_size,
                              hipStream_t stream)
{
    const float* A = (const float*)d_in[0];
    const float *w[6], *b[6], *p[6];
    for (int i = 0; i < 6; ++i) {
        w[i] = (const float*)d_in[1 + 3 * i];
        b[i] = (const float*)d_in[2 + 3 * i];
        p[i] = (const float*)d_in[3 + 3 * i];
    }

    auto footprint = [](long long S) -> size_t {
        auto al = [](size_t v) { return (v + 255) & ~(size_t)255; };
        size_t t = 0;
        t += al((size_t)HP * HP * 64 * 2);
        t += al((size_t)(S + 8) * HP * 256 * 2);
        t += al((size_t)(S + 6) * HP * 512 * 2);
        t += al((size_t)(S + 2) * HP * 64 * 2);
        t += al((size_t)512 * 512 * 4);
        t += al((size_t)9 * 256 * 64 * 2);
        t += al((size_t)9 * 512 * 256 * 2);
        t += al((size_t)9 * 256 * 512 * 2);
        t += al((size_t)9 * 64 * 256 * 2);
        t += al((size_t)9 * 64 * 2);
        return t;
    };
    const int cand[6] = {512, 256, 128, 64, 32, 16};
    int S = 16;
    for (int i = 0; i < 6; ++i)
        if (footprint(cand[i]) <= ws_size) { S = cand[i]; break; }
    const int nStrips = 512 / S;

    char* ws = (char*)d_ws;
    size_t off = 0;
    auto carve = [&](size_t bytes) -> void* {
        void* r = ws + off;
        off += (bytes + 255) & ~(size_t)255;
        return r;
    };
    bf16_t* X0  = (bf16_t*)carve((size_t)HP * HP * 64 * 2);
    bf16_t* B1  = (bf16_t*)carve((size_t)(S + 8) * HP * 256 * 2);
    bf16_t* B2  = (bf16_t*)carve((size_t)(S + 6) * HP * 512 * 2);
    bf16_t* B4  = (bf16_t*)carve((size_t)(S + 2) * HP * 64 * 2);
    float*  T   = (float*)carve((size_t)512 * 512 * 4);
    bf16_t* wt1 = (bf16_t*)carve((size_t)9 * 256 * 64 * 2);
    bf16_t* wt2 = (bf16_t*)carve((size_t)9 * 512 * 256 * 2);
    bf16_t* wt3 = (bf16_t*)carve((size_t)9 * 256 * 512 * 2);
    bf16_t* wt4 = (bf16_t*)carve((size_t)9 * 64 * 256 * 2);
    bf16_t* wt5 = (bf16_t*)carve((size_t)9 * 64 * 2);
    bf16_t* B3  = B1;   // alias: B1 dead after each strip's L2

    auto cdiv = [](int a, int bq) { return (a + bq - 1) / bq; };
    auto zrows = [&](bf16_t* buf, int C, int r0, int n) {
        if (n > 0)
            zero_rows_kernel<<<cdiv(n * HP * C, 256), 256, 0, stream>>>(buf, C, r0, n);
    };

    wtrans_kernel<<<cdiv(9 * 256 * 64, 256), 256, 0, stream>>>(w[1], wt1, 256, 64);
    wtrans_kernel<<<cdiv(9 * 512 * 256, 256), 256, 0, stream>>>(w[2], wt2, 512, 256);
    wtrans_kernel<<<cdiv(9 * 256 * 512, 256), 256, 0, stream>>>(w[3], wt3, 256, 512);
    wtrans_kernel<<<cdiv(9 * 64 * 256, 256), 256, 0, stream>>>(w[4], wt4, 64, 256);
    wtrans5_kernel<<<cdiv(9 * 64, 256), 256, 0, stream>>>(w[5], wt5);
    l0_kernel<<<cdiv(HP * HP * 64, 256), 256, 0, stream>>>(A, w[0], b[0], p[0], X0);
    zero_cols_kernel<<<cdiv((S + 8) * 2 * 256, 256), 256, 0, stream>>>(B1, 256, S + 8);
    zero_cols_kernel<<<cdiv((S + 6) * 2 * 512, 256), 256, 0, stream>>>(B2, 512, S + 6);
    zero_cols_kernel<<<cdiv((S + 2) * 2 * 64, 256), 256, 0, stream>>>(B4, 64, S + 2);

    for (int s = 0; s < nStrips; ++s) {
        const int base = S * s;
        int o0[5], nn[5], ooff[5], alloc[5];
        for (int k = 1; k <= 4; ++k) {
            int hk = 5 - k;                      // halos 4,3,2,1
            int a0 = base - hk, a1 = base + S + hk;
            int c0 = a0 < 0 ? 0 : a0, c1 = a1 > 512 ? 512 : a1;
            o0[k] = c0; nn[k] = c1 - c0; ooff[k] = c0 - a0; alloc[k] = S + 2 * hk;
        }
        // L1: X0 -> B1
        {
            int in_off = o0[1];
            dim3 g(64, cdiv(nn[1], 16), 2);
            conv3x3_kernel<64, 256, 128><<<g, 512, 0, stream>>>(
                X0, wt1, b[1], p[1], B1, nn[1], in_off, 514, ooff[1]);
            zrows(B1, 256, 0, ooff[1]);
            zrows(B1, 256, ooff[1] + nn[1], alloc[1] - ooff[1] - nn[1]);
        }
        // L2: B1 -> B2
        {
            int in_off = (o0[2] - 1) - (base - 4);
            dim3 g(64, cdiv(nn[2], 16), 4);
            conv3x3_kernel<256, 512, 128><<<g, 512, 0, stream>>>(
                B1, wt2, b[2], p[2], B2, nn[2], in_off, alloc[1], ooff[2]);
            zrows(B2, 512, 0, ooff[2]);
            zrows(B2, 512, ooff[2] + nn[2], alloc[2] - ooff[2] - nn[2]);
        }
        // L3: B2 -> B3
        {
            int in_off = (o0[3] - 1) - (base - 3);
            dim3 g(64, cdiv(nn[3], 16), 2);
            conv3x3_kernel<512, 256, 128><<<g, 512, 0, stream>>>(
                B2, wt3, b[3], p[3], B3, nn[3], in_off, alloc[2], ooff[3]);
            zrows(B3, 256, 0, ooff[3]);
            zrows(B3, 256, ooff[3] + nn[3], alloc[3] - ooff[3] - nn[3]);
        }
        // L4: B3 -> B4
        {
            int in_off = (o0[4] - 1) - (base - 2);
            dim3 g(64, cdiv(nn[4], 16), 1);
            conv3x3_kernel<256, 64, 64><<<g, 512, 0, stream>>>(
                B3, wt4, b[4], p[4], B4, nn[4], in_off, alloc[3], ooff[4]);
            zrows(B4, 64, 0, ooff[4]);
            zrows(B4, 64, ooff[4] + nn[4], alloc[4] - ooff[4] - nn[4]);
        }
        // L5
        l5_strip_kernel<<<(S * 512) / 256, 256, 0, stream>>>(B4, wt5, b[5], p[5], T, base);
    }

    sym_kernel<<<(512 * 512) / 256, 256, 0, stream>>>(T, (float*)d_out);
}

// Round 13
// 1343.213 us; speedup vs baseline: 1.1090x; 1.1090x over previous
//
#include <hip/hip_runtime.h>
#include <hip/hip_bf16.h>
#include <stdint.h>

typedef __bf16 bf16_t;
typedef __bf16 bf16x8 __attribute__((ext_vector_type(8)));
typedef float  f32x4  __attribute__((ext_vector_type(4)));

#define HP 514   // padded spatial width (512 + 2)
#define AS1 __attribute__((address_space(1)))
#define AS3 __attribute__((address_space(3)))

__device__ __forceinline__ bf16_t f2bf(float f) { return (bf16_t)f; }

// ---------- L0: 1->64 1x1 conv + PReLU; fp32 NCHW -> padded NHWC bf16 ----------
__global__ void l0_kernel(const float* __restrict__ A, const float* __restrict__ w0,
                          const float* __restrict__ b0, const float* __restrict__ p0,
                          bf16_t* __restrict__ X0)
{
    int idx = blockIdx.x * 256 + threadIdx.x;
    if (idx >= HP * HP * 64) return;
    int c   = idx & 63;
    int pix = idx >> 6;
    int py = pix / HP, px = pix - py * HP;
    float v = 0.f;
    if (py >= 1 && py <= 512 && px >= 1 && px <= 512) {
        float a = A[(py - 1) * 512 + (px - 1)];
        v = fmaf(w0[c], a, b0[c]);
        v = v >= 0.f ? v : p0[0] * v;
    }
    X0[idx] = f2bf(v);
}

// ---------- zero full rows [r0, r0+n) of a strip buffer ----------
__global__ void zero_rows_kernel(bf16_t* __restrict__ buf, int C, int r0, int n)
{
    int idx = blockIdx.x * 256 + threadIdx.x;
    int rowsz = HP * C;
    if (idx >= n * rowsz) return;
    int r = idx / rowsz, j = idx - r * rowsz;
    buf[(size_t)(r0 + r) * rowsz + j] = f2bf(0.f);
}

// ---------- zero cols 0 and 513 for rows [0, R) ----------
__global__ void zero_cols_kernel(bf16_t* __restrict__ buf, int C, int R)
{
    int idx = blockIdx.x * 256 + threadIdx.x;
    if (idx >= R * 2 * C) return;
    int r = idx / (2 * C);
    int t = idx - r * 2 * C;
    int col = (t < C) ? 0 : 513;
    int c = t % C;
    buf[((size_t)r * HP + col) * C + c] = f2bf(0.f);
}

// ---------- weight transform: OIHW fp32 -> MFMA-fragment-ordered bf16 ----------
// wt[(((ci*9 + tap)*G + gabs)*64 + l)*8 + j] = w[(cout*CIN+cin)*9 + tap]
//   cout = gabs*16 + (l&15), cin = ci*32 + (l>>4)*8 + j, G = COUT/16
// (correctness verified in R3/R4 runs)
__global__ void wtrans_kernel(const float* __restrict__ w, bf16_t* __restrict__ wt,
                              int COUT, int CIN)
{
    int idx = blockIdx.x * 256 + threadIdx.x;
    if (idx >= COUT * CIN * 9) return;
    int G    = COUT / 16;
    int j    = idx & 7;
    int l    = (idx >> 3) & 63;
    int t    = idx >> 9;
    int gabs = t % G;
    int t2   = t / G;
    int tap  = t2 % 9;
    int ci   = t2 / 9;
    int cout = gabs * 16 + (l & 15);
    int cin  = ci * 32 + (l >> 4) * 8 + j;
    wt[idx] = f2bf(w[(cout * CIN + cin) * 9 + tap]);
}

// ---------- 3x3 conv + bias + PReLU, implicit GEMM, bf16 MFMA ----------
// R6: B direct global->reg (wt fragment-ordered, L2-resident); A via
//     global_load_lds with inverse-swizzled source; barriers 1 per 9 taps.
// R7: A-fragment register prefetch (ping-pong) + s_setprio around MFMA.
// R9/R10: XCD-aware bijective swizzle, z-innermost; coalesced LDS epilogue.
// R17: FINAL — reverted to the measured-best R10 structure after the full
//      axis sweep: depth-2 B prefetch thrashes L2 (R8/R11); 4-slab A and
//      counted-vmcnt barriers are null (R12/R14); 32x32 MFMA kills acc ILP
//      (R13); 4-waves/SIMD occupancy regresses via doubled LDS traffic and
//      halved per-wave MFMA ILP (R15/R16). Converged plateau: ~63% MfmaUtil.
template<int CIN, int COUT, int BN>
__global__ __launch_bounds__(256, 3)
void conv3x3_kernel(const bf16_t* __restrict__ in, const bf16_t* __restrict__ wt,
                    const float* __restrict__ bias, const float* __restrict__ alpha,
                    bf16_t* __restrict__ out,
                    int n_rows, int in_off, int in_alloc, int out_off)
{
    constexpr int G      = COUT / 16;     // global cout groups (wt layout)
    constexpr int NT     = BN / 32;       // cout groups per wave (4 or 2)
    constexpr int NC     = CIN / 32;      // channel chunks (even: 2,8,16)
    constexpr int AUNITS = 18 * 10 * 4;   // 720 16B-units
    constexpr int APAD   = 768;           // padded to full 3x256 lanes
    constexpr int ASLAB  = APAD * 8;      // 6144 elems per A buffer
    constexpr int ROWB   = BN * 2;        // tile row bytes (256 or 128)
    constexpr int SMASK  = ROWB / 32 - 1; // XOR swizzle mask (7 or 3)
    constexpr int SMEM_B = (2 * ASLAB * 2 > 128 * ROWB) ? 2 * ASLAB * 2 : 128 * ROWB;
    __shared__ __align__(16) char smem[SMEM_B];
    bf16_t* As = (bf16_t*)smem;

    const int tid  = threadIdx.x;
    const int lane = tid & 63;
    const int wave = tid >> 6;
    const int lm   = lane & 15;
    const int quad = lane >> 4;
    const int wave_m = wave >> 1;
    const int wave_n = wave & 1;

    // ---- XCD swizzle: hw-linear bid -> chunked sid -> (z inner, x, y outer)
    const int bid  = blockIdx.x + 64 * (blockIdx.y + gridDim.y * blockIdx.z);
    const int nwg  = 64 * gridDim.y * gridDim.z;
    const int sid  = (bid & 7) * (nwg >> 3) + (bid >> 3);
    const int zsh  = __ffs(gridDim.z) - 1;          // gridDim.z in {1,2,4}
    const int szb  = sid & (gridDim.z - 1);
    const int t2   = sid >> zsh;
    const int sx   = t2 & 63;
    const int syb  = t2 >> 6;

    const int x0 = sx * 8;               // input col base (padded coords)
    const int y0 = syb * 16;             // local out row base
    const int zb = szb;
    const int gb_blk = zb * (BN / 16);

    // ---- A staging source map: 3 passes of 256 units; INVERSE swizzle on the
    // per-lane global address, LDS written linearly (unit w = pass*256+tid).
    int a_srcb[3];
    #pragma unroll
    for (int it = 0; it < 3; ++it) {
        int u  = it * 256 + tid;
        int uu = u < AUNITS ? u : AUNITS - 1;   // pad lanes re-read unit 719
        int qq = uu & 3, px = (uu >> 2) % 10, r = uu / 40;
        int q  = (qq - (px >> 1)) & 3;
        int grow = in_off + y0 + r;
        grow = grow < 0 ? 0 : (grow >= in_alloc ? in_alloc - 1 : grow);
        a_srcb[it] = (grow * HP + x0 + px) * CIN + q * 8;
    }

    // ---- fragment read bases (swizzled; unchanged from R4-verified) ----
    const int pxb = lm & 7, pyb = lm >> 3;
    int sw[3];
    #pragma unroll
    for (int dx = 0; dx < 3; ++dx)
        sw[dx] = ((quad + ((pxb + dx) >> 1)) & 3) * 8;
    int addrA0[4];
    #pragma unroll
    for (int mt = 0; mt < 4; ++mt)
        addrA0[mt] = ((wave_m * 8 + mt * 2 + pyb) * 40 + pxb * 4) * 8;

    auto stageA = [&](int cc, int abuf) {
        #pragma unroll
        for (int it = 0; it < 3; ++it) {
            const bf16_t* src = in + a_srcb[it] + cc;
            bf16_t* dst = As + abuf * ASLAB + (it * 256 + wave * 64) * 8;
            __builtin_amdgcn_global_load_lds((AS1 void*)src, (AS3 void*)dst, 16, 0, 0);
        }
    };
    // B fragments: direct global -> regs, coalesced 16B/lane (1 KB per group)
    auto loadB = [&](int ft, bf16x8* b) {
        const bf16_t* base = wt + ((size_t)ft * G + gb_blk + wave_n * NT) * 512 + lane * 8;
        #pragma unroll
        for (int nt = 0; nt < NT; ++nt)
            b[nt] = *(const bf16x8*)(base + nt * 512);
    };
    // A fragments for (slab ab, tap) -> registers (tap is compile-time)
    auto readA = [&](int ab, int tap, bf16x8* a) {
        const int dy = tap / 3, dx = tap - dy * 3;
        const int shift = (dy * 40 + dx * 4) * 8 + sw[dx];
        #pragma unroll
        for (int mt = 0; mt < 4; ++mt)
            a[mt] = *(const bf16x8*)(As + ab * ASLAB + addrA0[mt] + shift);
    };

    f32x4 acc[4][NT] = {};
    bf16x8 breg[2][NT];
    bf16x8 areg[2][4];

    // prologue: chunk-0 A -> As[0]; flat-0 B -> breg[0]; rf=0 A frags
    stageA(0, 0);
    loadB(0, breg[0]);
    __syncthreads();
    readA(0, 0, areg[0]);

    for (int cp = 0; cp < NC / 2; ++cp) {
        const bool morecp = (cp + 1 < NC / 2);
        const int fb = cp * 18;
        #pragma unroll
        for (int rf = 0; rf < 18; ++rf) {          // fully unrolled: all reg
            if (rf < 17 || morecp)                 // indices compile-time
                loadB(fb + rf + 1, breg[(rf + 1) & 1]);
            if (rf == 0)            stageA((2 * cp + 1) * 32, 1);
            if (rf == 9 && morecp)  stageA((2 * cp + 2) * 32, 0);
            // prefetch next phase's A fragments (same-slab phases only;
            // barrier-crossing phases 8/17 must read after their barrier)
            if (rf != 8 && rf != 17)
                readA((rf + 1) >= 9 ? 1 : 0, (rf + 1) % 9, areg[(rf + 1) & 1]);

            __builtin_amdgcn_s_setprio(1);
            #pragma unroll
            for (int mt = 0; mt < 4; ++mt)
                #pragma unroll
                for (int nt = 0; nt < NT; ++nt)
                    acc[mt][nt] = __builtin_amdgcn_mfma_f32_16x16x32_bf16(
                        areg[rf & 1][mt], breg[rf & 1][nt], acc[mt][nt], 0, 0, 0);
            __builtin_amdgcn_s_setprio(0);

            if (rf == 8) {
                __syncthreads();                   // As[1] now staged
                readA(1, 0, areg[1]);              // rf=9 frags (tap 0, slab 1)
            }
            if (rf == 17 && morecp) {
                __syncthreads();                   // As[0] now holds chunk 2cp+2
                readA(0, 0, areg[0]);              // next cp rf=0 frags
            }
        }
    }

    // ---- epilogue: bias + PReLU -> LDS tile (XOR-swizzled cols) ->
    //      coalesced bf16x8 copy-out (R10-verified).
    __syncthreads();                               // all As reads done; reuse smem
    const float al = alpha[0];
    #pragma unroll
    for (int nt = 0; nt < NT; ++nt) {
        const int c  = wave_n * (BN / 2) + nt * 16 + lm;
        const float bv = bias[zb * BN + c];
        #pragma unroll
        for (int mt = 0; mt < 4; ++mt) {
            f32x4 v = acc[mt][nt];
            #pragma unroll
            for (int r = 0; r < 4; ++r) {
                int m = wave_m * 64 + mt * 16 + quad * 4 + r;
                float f = v[r] + bv;
                f = f >= 0.f ? f : al * f;
                int byte = m * ROWB + ((c * 2) ^ ((m & SMASK) << 5));
                *(bf16_t*)(smem + byte) = f2bf(f);
            }
        }
    }
    __syncthreads();
    constexpr int CPI  = ROWB / 16;                // 16B chunks per pixel
    constexpr int ITER = (128 * CPI) / 256;        // copy iterations
    #pragma unroll
    for (int i = 0; i < ITER; ++i) {
        int g = i * 256 + tid;
        int p = g / CPI;                           // pixel 0..127
        int k = g & (CPI - 1);                     // 16B chunk in row
        int sbyte = p * ROWB + ((k * 16) ^ ((p & SMASK) << 5));
        bf16x8 v16 = *(const bf16x8*)(smem + sbyte);
        int py = p >> 3, px = p & 7, ly = y0 + py;
        if (ly < n_rows)
            *(bf16x8*)(out + ((size_t)(out_off + ly) * HP + (x0 + px + 1)) * COUT
                       + zb * BN + k * 8) = v16;
    }
}

// ---------- L5 (64->1, k3) + bias + PReLU per strip, fp32 T out ----------
__device__ __forceinline__ float conv64_at(const bf16_t* __restrict__ X,
                                           const float* __restrict__ wsh,
                                           int y, int x, float bv)
{
    float acc = bv;
    #pragma unroll
    for (int dy = 0; dy < 3; ++dy) {
        #pragma unroll
        for (int dx = 0; dx < 3; ++dx) {
            const bf16x8* p = (const bf16x8*)(X + ((size_t)(y + dy) * HP + (x + dx)) * 64);
            const float* wf = wsh + (dy * 3 + dx) * 64;
            #pragma unroll
            for (int j = 0; j < 8; ++j) {
                bf16x8 v = p[j];
                #pragma unroll
                for (int k = 0; k < 8; ++k)
                    acc = fmaf((float)v[k], wf[j * 8 + k], acc);
            }
        }
    }
    return acc;
}

__global__ __launch_bounds__(256)
void l5_strip_kernel(const bf16_t* __restrict__ B4, const bf16_t* __restrict__ wt5,
                     const float* __restrict__ b5, const float* __restrict__ p5,
                     float* __restrict__ T, int abs_row0)
{
    __shared__ float wsh[9 * 64];
    for (int i = threadIdx.x; i < 576; i += 256) wsh[i] = (float)wt5[i];
    __syncthreads();
    int idx = blockIdx.x * 256 + threadIdx.x;
    int ly = idx >> 9, x = idx & 511;
    float bv = b5[0], al = p5[0];
    float t = conv64_at(B4, wsh, ly, x, bv);
    t = t >= 0.f ? t : al * t;
    T[(size_t)(abs_row0 + ly) * 512 + x] = t;
}

// ---------- weight transform for L5 (plain [tap][cin], tiny) ----------
__global__ void wtrans5_kernel(const float* __restrict__ w, bf16_t* __restrict__ wt)
{
    int idx = blockIdx.x * 256 + threadIdx.x;
    if (idx >= 9 * 64) return;
    int cin = idx % 64, tap = idx / 64;
    wt[idx] = f2bf(w[cin * 9 + tap]);
}

// ---------- final symmetrize ----------
__global__ __launch_bounds__(256)
void sym_kernel(const float* __restrict__ T, float* __restrict__ out)
{
    int idx = blockIdx.x * 256 + threadIdx.x;
    int y = idx >> 9, x = idx & 511;
    out[idx] = 0.5f * (T[idx] + T[x * 512 + y]);
}

// ----------------------------------------------------------------------------
extern "C" void kernel_launch(void* const* d_in, const int* in_sizes, int n_in,
                              void* d_out, int out_size, void* d_ws, size_t ws_size,
                              hipStream_t stream)
{
    const float* A = (const float*)d_in[0];
    const float *w[6], *b[6], *p[6];
    for (int i = 0; i < 6; ++i) {
        w[i] = (const float*)d_in[1 + 3 * i];
        b[i] = (const float*)d_in[2 + 3 * i];
        p[i] = (const float*)d_in[3 + 3 * i];
    }

    auto footprint = [](long long S) -> size_t {
        auto al = [](size_t v) { return (v + 255) & ~(size_t)255; };
        size_t t = 0;
        t += al((size_t)HP * HP * 64 * 2);
        t += al((size_t)(S + 8) * HP * 256 * 2);
        t += al((size_t)(S + 6) * HP * 512 * 2);
        t += al((size_t)(S + 2) * HP * 64 * 2);
        t += al((size_t)512 * 512 * 4);
        t += al((size_t)9 * 256 * 64 * 2);
        t += al((size_t)9 * 512 * 256 * 2);
        t += al((size_t)9 * 256 * 512 * 2);
        t += al((size_t)9 * 64 * 256 * 2);
        t += al((size_t)9 * 64 * 2);
        return t;
    };
    const int cand[6] = {512, 256, 128, 64, 32, 16};
    int S = 16;
    for (int i = 0; i < 6; ++i)
        if (footprint(cand[i]) <= ws_size) { S = cand[i]; break; }
    const int nStrips = 512 / S;

    char* ws = (char*)d_ws;
    size_t off = 0;
    auto carve = [&](size_t bytes) -> void* {
        void* r = ws + off;
        off += (bytes + 255) & ~(size_t)255;
        return r;
    };
    bf16_t* X0  = (bf16_t*)carve((size_t)HP * HP * 64 * 2);
    bf16_t* B1  = (bf16_t*)carve((size_t)(S + 8) * HP * 256 * 2);
    bf16_t* B2  = (bf16_t*)carve((size_t)(S + 6) * HP * 512 * 2);
    bf16_t* B4  = (bf16_t*)carve((size_t)(S + 2) * HP * 64 * 2);
    float*  T   = (float*)carve((size_t)512 * 512 * 4);
    bf16_t* wt1 = (bf16_t*)carve((size_t)9 * 256 * 64 * 2);
    bf16_t* wt2 = (bf16_t*)carve((size_t)9 * 512 * 256 * 2);
    bf16_t* wt3 = (bf16_t*)carve((size_t)9 * 256 * 512 * 2);
    bf16_t* wt4 = (bf16_t*)carve((size_t)9 * 64 * 256 * 2);
    bf16_t* wt5 = (bf16_t*)carve((size_t)9 * 64 * 2);
    bf16_t* B3  = B1;   // alias: B1 dead after each strip's L2

    auto cdiv = [](int a, int bq) { return (a + bq - 1) / bq; };
    auto zrows = [&](bf16_t* buf, int C, int r0, int n) {
        if (n > 0)
            zero_rows_kernel<<<cdiv(n * HP * C, 256), 256, 0, stream>>>(buf, C, r0, n);
    };

    wtrans_kernel<<<cdiv(9 * 256 * 64, 256), 256, 0, stream>>>(w[1], wt1, 256, 64);
    wtrans_kernel<<<cdiv(9 * 512 * 256, 256), 256, 0, stream>>>(w[2], wt2, 512, 256);
    wtrans_kernel<<<cdiv(9 * 256 * 512, 256), 256, 0, stream>>>(w[3], wt3, 256, 512);
    wtrans_kernel<<<cdiv(9 * 64 * 256, 256), 256, 0, stream>>>(w[4], wt4, 64, 256);
    wtrans5_kernel<<<cdiv(9 * 64, 256), 256, 0, stream>>>(w[5], wt5);
    l0_kernel<<<cdiv(HP * HP * 64, 256), 256, 0, stream>>>(A, w[0], b[0], p[0], X0);
    zero_cols_kernel<<<cdiv((S + 8) * 2 * 256, 256), 256, 0, stream>>>(B1, 256, S + 8);
    zero_cols_kernel<<<cdiv((S + 6) * 2 * 512, 256), 256, 0, stream>>>(B2, 512, S + 6);
    zero_cols_kernel<<<cdiv((S + 2) * 2 * 64, 256), 256, 0, stream>>>(B4, 64, S + 2);

    for (int s = 0; s < nStrips; ++s) {
        const int base = S * s;
        int o0[5], nn[5], ooff[5], alloc[5];
        for (int k = 1; k <= 4; ++k) {
            int hk = 5 - k;                      // halos 4,3,2,1
            int a0 = base - hk, a1 = base + S + hk;
            int c0 = a0 < 0 ? 0 : a0, c1 = a1 > 512 ? 512 : a1;
            o0[k] = c0; nn[k] = c1 - c0; ooff[k] = c0 - a0; alloc[k] = S + 2 * hk;
        }
        // L1: X0 -> B1
        {
            int in_off = o0[1];
            dim3 g(64, cdiv(nn[1], 16), 2);
            conv3x3_kernel<64, 256, 128><<<g, 256, 0, stream>>>(
                X0, wt1, b[1], p[1], B1, nn[1], in_off, 514, ooff[1]);
            zrows(B1, 256, 0, ooff[1]);
            zrows(B1, 256, ooff[1] + nn[1], alloc[1] - ooff[1] - nn[1]);
        }
        // L2: B1 -> B2
        {
            int in_off = (o0[2] - 1) - (base - 4);
            dim3 g(64, cdiv(nn[2], 16), 4);
            conv3x3_kernel<256, 512, 128><<<g, 256, 0, stream>>>(
                B1, wt2, b[2], p[2], B2, nn[2], in_off, alloc[1], ooff[2]);
            zrows(B2, 512, 0, ooff[2]);
            zrows(B2, 512, ooff[2] + nn[2], alloc[2] - ooff[2] - nn[2]);
        }
        // L3: B2 -> B3
        {
            int in_off = (o0[3] - 1) - (base - 3);
            dim3 g(64, cdiv(nn[3], 16), 2);
            conv3x3_kernel<512, 256, 128><<<g, 256, 0, stream>>>(
                B2, wt3, b[3], p[3], B3, nn[3], in_off, alloc[2], ooff[3]);
            zrows(B3, 256, 0, ooff[3]);
            zrows(B3, 256, ooff[3] + nn[3], alloc[3] - ooff[3] - nn[3]);
        }
        // L4: B3 -> B4
        {
            int in_off = (o0[4] - 1) - (base - 2);
            dim3 g(64, cdiv(nn[4], 16), 1);
            conv3x3_kernel<256, 64, 64><<<g, 256, 0, stream>>>(
                B3, wt4, b[4], p[4], B4, nn[4], in_off, alloc[3], ooff[4]);
            zrows(B4, 64, 0, ooff[4]);
            zrows(B4, 64, ooff[4] + nn[4], alloc[4] - ooff[4] - nn[4]);
        }
        // L5
        l5_strip_kernel<<<(S * 512) / 256, 256, 0, stream>>>(B4, wt5, b[5], p[5], T, base);
    }

    sym_kernel<<<(512 * 512) / 256, 256, 0, stream>>>(T, (float*)d_out);
}